// Round 9
// baseline (101.725 us; speedup 1.0000x reference)
//
#include <hip/hip_runtime.h>
#include <hip/hip_bf16.h>

typedef float    f32x4 __attribute__((ext_vector_type(4)));
typedef _Float16 f16x8 __attribute__((ext_vector_type(8)));
typedef _Float16 f16x4 __attribute__((ext_vector_type(4)));
typedef __fp16   fp16x2 __attribute__((ext_vector_type(2)));

#define NN 4096
#define INF_ 256
#define OUTF 64
#define NH 4
#define NSPL 8
#define NGRP 128            // NN/32
#define LOG2E 1.4426950408889634f

// ---------------------------------------------------------------------------
// K0: pack adj (0/1 floats) into bitmask; diagonal forced 1; init smax.
// ---------------------------------------------------------------------------
__global__ __launch_bounds__(256) void k0_pack(const float* __restrict__ adj,
                                               unsigned* __restrict__ pack,
                                               unsigned* __restrict__ smax)
{
    const int r    = blockIdx.x;
    const int w    = threadIdx.x >> 6;
    const int lane = threadIdx.x & 63;
    const float* row = adj + (size_t)r * NN + w * 1024;
#pragma unroll
    for (int i = 0; i < 4; ++i) {
        float a0 = row[i*256 + lane];
        float a1 = row[i*256 +  64 + lane];
        float a2 = row[i*256 + 128 + lane];
        float a3 = row[i*256 + 192 + lane];
        unsigned long long bal[4];
        bal[0] = __ballot(a0 != 0.f);
        bal[1] = __ballot(a1 != 0.f);
        bal[2] = __ballot(a2 != 0.f);
        bal[3] = __ballot(a3 != 0.f);
        if (lane < 2) {
#pragma unroll
            for (int k = 0; k < 4; ++k) {
                int wi = w*32 + i*8 + k*2 + lane;
                unsigned v = (unsigned)(bal[k] >> (lane * 32));
                if (wi == (r >> 5)) v |= 1u << (r & 31);   // diagonal
                pack[r*128 + wi] = v;
            }
        }
    }
    if (r == 0 && threadIdx.x < NH) smax[threadIdx.x] = 0u;
}

__device__ __forceinline__ unsigned enc_f32(float f) {
    unsigned u = __float_as_uint(f);
    return (u & 0x80000000u) ? ~u : (u | 0x80000000u);
}
__device__ __forceinline__ float dec_f32(unsigned u) {
    return (u & 0x80000000u) ? __uint_as_float(u ^ 0x80000000u)
                             : __uint_as_float(~u);
}

// ---------------------------------------------------------------------------
// KW: transpose W into MFMA-B fragment-native f16, split hi/lo.
// ---------------------------------------------------------------------------
__global__ __launch_bounds__(256) void kW_tr(const float* __restrict__ W,
                                             _Float16* __restrict__ wBh,
                                             _Float16* __restrict__ wBl)
{
    const int b = blockIdx.x;
    const int h = b >> 3, ks = b & 7;
    const int t = threadIdx.x;
    const int ob = t >> 6, lane = t & 63;
    const int row16 = lane & 15, quad = lane >> 4;

    const float* wp = W + (size_t)h*INF_*OUTF + (ks*32 + quad*8)*OUTF + ob*16 + row16;
    f16x8 vh, vl;
#pragma unroll
    for (int e = 0; e < 8; ++e) {
        float v = wp[e*OUTF];
        _Float16 hi = (_Float16)v;
        vh[e] = hi;
        vl[e] = (_Float16)(v - (float)hi);
    }
    const int idx = ((h*8 + ks)*4 + ob)*64 + lane;
    reinterpret_cast<f16x8*>(wBh)[idx] = vh;
    reinterpret_cast<f16x8*>(wBl)[idx] = vl;
}

// ---------------------------------------------------------------------------
// K1m v2: Wh = x @ W via MFMA, 3-term double-f16 split (f32-accurate).
// Grid 1024 = (h, 16-row group); 4 waves = 4 obs (16 cols each), K=256.
// 4 blocks/CU, 16 waves/CU (v1 had 1 wave/SIMD -> latency-bound, 20+ us).
// Epilogue: whB fragment-native store; s_src/s_dst via shfl + LDS cross-
// wave reduce; smax atomicMax.
// ---------------------------------------------------------------------------
__global__ __launch_bounds__(256) void k1m(
    const float* __restrict__ x, const _Float16* __restrict__ wBh,
    const _Float16* __restrict__ wBl, const float* __restrict__ a,
    _Float16* __restrict__ whB, float* __restrict__ s_src,
    float* __restrict__ s_dst, unsigned* __restrict__ smax)
{
    __shared__ float red_s[4][16];
    __shared__ float red_d[4][16];

    const int b = blockIdx.x;
    const int h = b >> 8, g = b & 255;
    const int n0 = g * 16;
    const int ob = threadIdx.x >> 6;
    const int lane = threadIdx.x & 63;
    const int row16 = lane & 15, quad = lane >> 4;

    f32x4 acc = {0,0,0,0};
    const float* xp = x + (size_t)(n0 + row16)*INF_ + quad*8;
    const f16x8* WH = reinterpret_cast<const f16x8*>(wBh) + h*2048 + ob*64 + lane;
    const f16x8* WL = reinterpret_cast<const f16x8*>(wBl) + h*2048 + ob*64 + lane;

#pragma unroll
    for (int ks = 0; ks < 8; ++ks) {
        float4 xv0 = *reinterpret_cast<const float4*>(xp + ks*32);
        float4 xv1 = *reinterpret_cast<const float4*>(xp + ks*32 + 4);
        const float xv[8] = {xv0.x,xv0.y,xv0.z,xv0.w,xv1.x,xv1.y,xv1.z,xv1.w};
        f16x8 Ah, Al;
#pragma unroll
        for (int e = 0; e < 8; ++e) {
            _Float16 hi = (_Float16)xv[e];
            Ah[e] = hi;
            Al[e] = (_Float16)(xv[e] - (float)hi);
        }
        f16x8 bh = WH[ks*256];
        f16x8 bl = WL[ks*256];
        acc = __builtin_amdgcn_mfma_f32_16x16x32_f16(Ah, bh, acc, 0, 0, 0);
        acc = __builtin_amdgcn_mfma_f32_16x16x32_f16(Al, bh, acc, 0, 0, 0);
        acc = __builtin_amdgcn_mfma_f32_16x16x32_f16(Ah, bl, acc, 0, 0, 0);
    }

    // ---- whB fragment-native store (8B) ----
    {
        const int jblk = n0 >> 5;
        const int qb   = ((n0 & 16) >> 3) + (quad >> 1);
        const int e0   = (quad & 1) * 4;
        f16x4 st;
#pragma unroll
        for (int q = 0; q < 4; ++q) st[q] = (_Float16)acc[q];
        const size_t off = (((size_t)(h*NGRP + jblk)*4 + ob)*64 + qb*16 + row16)*8 + e0;
        *reinterpret_cast<f16x4*>(whB + off) = st;
    }

    // ---- partial s-dots (this wave's 16 cols), shfl-reduce over cols ----
    const float as = a[h*128 + ob*16 + row16];
    const float ad = a[h*128 + 64 + ob*16 + row16];
#pragma unroll
    for (int q = 0; q < 4; ++q) {
        float vs = acc[q] * as;
        float vd = acc[q] * ad;
#pragma unroll
        for (int m = 1; m <= 8; m <<= 1) {
            vs += __shfl_xor(vs, m);
            vd += __shfl_xor(vd, m);
        }
        if (row16 == 0) {
            red_s[ob][quad*4 + q] = vs;
            red_d[ob][quad*4 + q] = vd;
        }
    }
    __syncthreads();
    if (threadIdx.x < 16) {
        const int r = threadIdx.x;
        const float vs = red_s[0][r] + red_s[1][r] + red_s[2][r] + red_s[3][r];
        const float vd = red_d[0][r] + red_d[1][r] + red_d[2][r] + red_d[3][r];
        const float sd = LOG2E * vd;
        s_src[h*NN + n0 + r] = LOG2E * vs;
        s_dst[h*NN + n0 + r] = sd;
        float vmax = sd;
#pragma unroll
        for (int m = 1; m <= 8; m <<= 1) vmax = fmaxf(vmax, __shfl_xor(vmax, m));
        if (r == 0) atomicMax(&smax[h], enc_f32(vmax));
    }
}

// ---------------------------------------------------------------------------
// K3: barrier-free fused softmax + P@Wh. Partials packed f16 (cvt_pkrtz).
// ---------------------------------------------------------------------------
template <int USE_PART>
__global__ __launch_bounds__(256, 4) void k3_attn(
    const unsigned* __restrict__ pack, const _Float16* __restrict__ whB,
    const float* __restrict__ s_src, const float* __restrict__ s_dst,
    const unsigned* __restrict__ smax_enc,
    float* __restrict__ outp, float* __restrict__ l_ws)
{
    constexpr int STEPS_ = NN / NSPL / 32;   // 16

    const int b      = blockIdx.x;
    const int jsplit = b % NSPL;
    const int r2     = b / NSPL;
    const int hh     = r2 & 3;
    const int grp    = r2 >> 2;
    const int w      = threadIdx.x >> 6;
    const int lane   = threadIdx.x & 63;
    const int row16  = lane & 15;
    const int quad   = lane >> 4;
    const int i0     = (grp * 4 + w) * 32;
    const int jb0    = jsplit * (NN / NSPL);
    const int jblk0  = jb0 >> 5;

    const float sm = dec_f32(smax_enc[hh]);
    float A1[2], A2[2];
    const unsigned* prow[2];
#pragma unroll
    for (int f = 0; f < 2; ++f) {
        const int ir = i0 + f*16 + row16;
        const float s_i = s_src[hh*NN + ir];
        const float zb  = s_i + sm;
        const float mb  = fmaxf(zb, 0.2f * zb);
        A1[f] = s_i - mb;
        A2[f] = 0.2f * s_i - mb;
        prow[f] = pack + ir*128 + jblk0;
    }

    f32x4 acc[2][4];
    f32x4 accl[2];
#pragma unroll
    for (int f = 0; f < 2; ++f) {
        accl[f] = (f32x4){0,0,0,0};
#pragma unroll
        for (int ob = 0; ob < 4; ++ob) acc[f][ob] = (f32x4){0,0,0,0};
    }

    f16x8 ones;
#pragma unroll
    for (int e = 0; e < 8; ++e) ones[e] = (_Float16)1.0f;

    const _Float16* bB  = whB + (size_t)(hh*NGRP + jblk0)*2048 + lane*8;
    const float*    sdp = s_dst + hh*NN + jb0 + quad*8;

    f16x8 B0 = *reinterpret_cast<const f16x8*>(bB);
    f16x8 B1 = *reinterpret_cast<const f16x8*>(bB + 512);
    f16x8 B2 = *reinterpret_cast<const f16x8*>(bB + 1024);
    f16x8 B3 = *reinterpret_cast<const f16x8*>(bB + 1536);
    unsigned msk0 = prow[0][0], msk1 = prow[1][0];
    float4 sj0 = *reinterpret_cast<const float4*>(sdp);
    float4 sj1 = *reinterpret_cast<const float4*>(sdp + 4);

    for (int s = 0; s < STEPS_; ++s) {
        const _Float16* bn = bB + (s+1)*2048;
        f16x8 nB0 = *reinterpret_cast<const f16x8*>(bn);
        f16x8 nB1 = *reinterpret_cast<const f16x8*>(bn + 512);
        f16x8 nB2 = *reinterpret_cast<const f16x8*>(bn + 1024);
        f16x8 nB3 = *reinterpret_cast<const f16x8*>(bn + 1536);
        unsigned nmsk0 = prow[0][s+1], nmsk1 = prow[1][s+1];
        float4 nsj0 = *reinterpret_cast<const float4*>(sdp + (s+1)*32);
        float4 nsj1 = *reinterpret_cast<const float4*>(sdp + (s+1)*32 + 4);

        const float sjv[8] = {sj0.x,sj0.y,sj0.z,sj0.w,sj1.x,sj1.y,sj1.z,sj1.w};
        float us[8];
#pragma unroll
        for (int e = 0; e < 8; ++e) us[e] = 0.2f * sjv[e];

        const unsigned mskf[2] = {msk0, msk1};
#pragma unroll
        for (int f = 0; f < 2; ++f) {
            const unsigned mm8 = (mskf[f] >> (quad * 8)) & 0xffu;
            float pe[8];
#pragma unroll
            for (int e = 0; e < 8; ++e) {
                float t1 = A1[f] + sjv[e];
                float t2 = A2[f] + us[e];
                float p  = __builtin_amdgcn_exp2f(fmaxf(t1, t2));
                pe[e] = (mm8 & (1u << e)) ? p : 0.0f;
            }
            union { f16x8 v8; fp16x2 p2[4]; } pa;
#pragma unroll
            for (int e2 = 0; e2 < 4; ++e2)
                pa.p2[e2] = __builtin_amdgcn_cvt_pkrtz(pe[2*e2], pe[2*e2+1]);

            acc[f][0] = __builtin_amdgcn_mfma_f32_16x16x32_f16(pa.v8, B0, acc[f][0], 0, 0, 0);
            acc[f][1] = __builtin_amdgcn_mfma_f32_16x16x32_f16(pa.v8, B1, acc[f][1], 0, 0, 0);
            acc[f][2] = __builtin_amdgcn_mfma_f32_16x16x32_f16(pa.v8, B2, acc[f][2], 0, 0, 0);
            acc[f][3] = __builtin_amdgcn_mfma_f32_16x16x32_f16(pa.v8, B3, acc[f][3], 0, 0, 0);
            accl[f]   = __builtin_amdgcn_mfma_f32_16x16x32_f16(pa.v8, ones, accl[f], 0, 0, 0);
        }

        B0 = nB0; B1 = nB1; B2 = nB2; B3 = nB3;
        msk0 = nmsk0; msk1 = nmsk1;
        sj0 = nsj0; sj1 = nsj1;
    }

#pragma unroll
    for (int f = 0; f < 2; ++f) {
        if (row16 == 0) {
#pragma unroll
            for (int q = 0; q < 4; ++q) {
                const int ir = i0 + f*16 + quad*4 + q;
                if (USE_PART) l_ws[(jsplit*NH + hh)*NN + ir] = accl[f][q];
                else          atomicAdd(&l_ws[hh*NN + ir], accl[f][q]);
            }
        }
    }
    if (USE_PART) {
        // packed-f16 wave-native partials: u32 word = (q0,q1) / (q2,q3)
        unsigned* pw = reinterpret_cast<unsigned*>(outp)
                     + ((size_t)((jsplit*NH + hh)*NGRP + (i0 >> 5))) * 1024 + lane;
#pragma unroll
        for (int f = 0; f < 2; ++f)
#pragma unroll
            for (int ob = 0; ob < 4; ++ob) {
                union { fp16x2 h2; unsigned u; } p0, p1;
                p0.h2 = __builtin_amdgcn_cvt_pkrtz(acc[f][ob][0], acc[f][ob][1]);
                p1.h2 = __builtin_amdgcn_cvt_pkrtz(acc[f][ob][2], acc[f][ob][3]);
                pw[((f*4 + ob)*2 + 0)*64] = p0.u;
                pw[((f*4 + ob)*2 + 1)*64] = p1.u;
            }
    } else {
#pragma unroll
        for (int f = 0; f < 2; ++f)
#pragma unroll
            for (int ob = 0; ob < 4; ++ob)
#pragma unroll
                for (int q = 0; q < 4; ++q) {
                    const int grow = i0 + f*16 + quad*4 + q;
                    const int gcol = hh*OUTF + ob*16 + row16;
                    atomicAdd(&outp[(size_t)grow*256 + gcol], acc[f][ob][q]);
                }
    }
}

// ---------------------------------------------------------------------------
// K4 (partials): unscramble packed-f16 partials, out = sum(part)/sum(l)
// ---------------------------------------------------------------------------
__global__ __launch_bounds__(256) void k4_part(const unsigned* __restrict__ part,
                                               const float* __restrict__ l_ws,
                                               float* __restrict__ out)
{
    const int idx = blockIdx.x * 256 + threadIdx.x;   // f32x4 index, < 262144
    const int n = idx >> 6, c4 = idx & 63;
    const int h = c4 >> 4, k = c4 & 15;
    const int g = n >> 5, f = (n >> 4) & 1, quad = (n >> 2) & 3, q = n & 3;
    const int ob = k >> 2, lb = quad*16 + (k & 3)*4;
    const int wi = ((f*4 + ob)*2 + (q >> 1))*64 + lb;
    const int hsel = q & 1;

    float L = 0.f;
    f32x4 v = {0,0,0,0};
#pragma unroll
    for (int sp = 0; sp < NSPL; ++sp) {
        L += l_ws[(sp*NH + h)*NN + n];
        union { uint4 u4; _Float16 hx[8]; } uu;
        uu.u4 = *reinterpret_cast<const uint4*>(part + ((size_t)((sp*NH + h)*NGRP + g))*1024 + wi);
#pragma unroll
        for (int i = 0; i < 4; ++i) v[i] += (float)uu.hx[i*2 + hsel];
    }
    const float inv = 1.0f / L;
    *reinterpret_cast<f32x4*>(out + (size_t)n*256 + c4*4) = v * inv;
}

// K4 (atomic fallback): out /= l
__global__ __launch_bounds__(256) void k4_atomic(float* __restrict__ out,
                                                 const float* __restrict__ l_acc)
{
    const int idx = blockIdx.x * 256 + threadIdx.x;
    const int n = idx >> 6, c4 = idx & 63, h = c4 >> 4;
    const float inv = 1.0f / l_acc[h*NN + n];
    f32x4 v = *reinterpret_cast<f32x4*>(out + (size_t)n*256 + c4*4);
    *reinterpret_cast<f32x4*>(out + (size_t)n*256 + c4*4) = v * inv;
}

extern "C" void kernel_launch(void* const* d_in, const int* in_sizes, int n_in,
                              void* d_out, int out_size, void* d_ws, size_t ws_size,
                              hipStream_t stream)
{
    const float* x   = (const float*)d_in[0];
    const float* adj = (const float*)d_in[1];
    const float* W   = (const float*)d_in[2];
    const float* a   = (const float*)d_in[3];
    float* out = (float*)d_out;

    char* ws = (char*)d_ws;
    _Float16* whB  = (_Float16*)ws;                              // 2 MB
    unsigned* pack = (unsigned*)(ws + (2u<<20));                 // 2 MB
    _Float16* wBh  = (_Float16*)(ws + (4u<<20));                 // 128 KB
    _Float16* wBl  = (_Float16*)(ws + (4u<<20) + (128u<<10));    // 128 KB
    float* s_src   = (float*)(ws + (4u<<20) + (256u<<10));       // 64 KB
    float* s_dst   = (float*)(ws + (4u<<20) + (320u<<10));       // 64 KB
    unsigned* smax = (unsigned*)(ws + (4u<<20) + (384u<<10));    // 1 KB slot
    float* l_ws    = (float*)(ws + (4u<<20) + (385u<<10));       // 512 KB
    char*  partb   = ws + (4u<<20) + (897u<<10);                 // 16 MB (f16-packed)

    const size_t need = (4u<<20) + (897u<<10) + (size_t)NSPL * NN * 256 * 2;

    k0_pack<<<NN, 256, 0, stream>>>(adj, pack, smax);
    kW_tr  <<<32, 256, 0, stream>>>(W, wBh, wBl);
    k1m    <<<1024, 256, 0, stream>>>(x, wBh, wBl, a, whB, s_src, s_dst, smax);

    if (ws_size >= need) {
        k3_attn<1><<<1024, 256, 0, stream>>>(pack, whB, s_src, s_dst, smax,
                                             (float*)partb, l_ws);
        k4_part<<<1024, 256, 0, stream>>>((const unsigned*)partb, l_ws, out);
    } else {
        (void)hipMemsetAsync(d_out, 0, (size_t)out_size * sizeof(float), stream);
        (void)hipMemsetAsync(l_ws, 0, NH * NN * sizeof(float), stream);
        k3_attn<0><<<1024, 256, 0, stream>>>(pack, whB, s_src, s_dst, smax, out, l_ws);
        k4_atomic<<<1024, 256, 0, stream>>>(out, l_ws);
    }
}

// Round 10
// 97.772 us; speedup vs baseline: 1.0404x; 1.0404x over previous
//
#include <hip/hip_runtime.h>
#include <hip/hip_bf16.h>

typedef float    f32x4 __attribute__((ext_vector_type(4)));
typedef _Float16 f16x8 __attribute__((ext_vector_type(8)));
typedef _Float16 f16x4 __attribute__((ext_vector_type(4)));
typedef __fp16   fp16x2 __attribute__((ext_vector_type(2)));

#define NN 4096
#define INF_ 256
#define OUTF 64
#define NH 4
#define NSPL 8
#define NGRP 128            // NN/32
#define LOG2E 1.4426950408889634f

// ---------------------------------------------------------------------------
// K0: pack adj (0/1 floats) into bitmask; diagonal forced 1; init smax.
// ---------------------------------------------------------------------------
__global__ __launch_bounds__(256) void k0_pack(const float* __restrict__ adj,
                                               unsigned* __restrict__ pack,
                                               unsigned* __restrict__ smax)
{
    const int r    = blockIdx.x;
    const int w    = threadIdx.x >> 6;
    const int lane = threadIdx.x & 63;
    const float* row = adj + (size_t)r * NN + w * 1024;
#pragma unroll
    for (int i = 0; i < 4; ++i) {
        float a0 = row[i*256 + lane];
        float a1 = row[i*256 +  64 + lane];
        float a2 = row[i*256 + 128 + lane];
        float a3 = row[i*256 + 192 + lane];
        unsigned long long bal[4];
        bal[0] = __ballot(a0 != 0.f);
        bal[1] = __ballot(a1 != 0.f);
        bal[2] = __ballot(a2 != 0.f);
        bal[3] = __ballot(a3 != 0.f);
        if (lane < 2) {
#pragma unroll
            for (int k = 0; k < 4; ++k) {
                int wi = w*32 + i*8 + k*2 + lane;
                unsigned v = (unsigned)(bal[k] >> (lane * 32));
                if (wi == (r >> 5)) v |= 1u << (r & 31);   // diagonal
                pack[r*128 + wi] = v;
            }
        }
    }
    if (r == 0 && threadIdx.x < NH) smax[threadIdx.x] = 0u;
}

__device__ __forceinline__ unsigned enc_f32(float f) {
    unsigned u = __float_as_uint(f);
    return (u & 0x80000000u) ? ~u : (u | 0x80000000u);
}
__device__ __forceinline__ float dec_f32(unsigned u) {
    return (u & 0x80000000u) ? __uint_as_float(u ^ 0x80000000u)
                             : __uint_as_float(~u);
}

// ---------------------------------------------------------------------------
// KW: transpose W into MFMA-B fragment-native f16, split hi/lo.
// ---------------------------------------------------------------------------
__global__ __launch_bounds__(256) void kW_tr(const float* __restrict__ W,
                                             _Float16* __restrict__ wBh,
                                             _Float16* __restrict__ wBl)
{
    const int b = blockIdx.x;
    const int h = b >> 3, ks = b & 7;
    const int t = threadIdx.x;
    const int ob = t >> 6, lane = t & 63;
    const int row16 = lane & 15, quad = lane >> 4;

    const float* wp = W + (size_t)h*INF_*OUTF + (ks*32 + quad*8)*OUTF + ob*16 + row16;
    f16x8 vh, vl;
#pragma unroll
    for (int e = 0; e < 8; ++e) {
        float v = wp[e*OUTF];
        _Float16 hi = (_Float16)v;
        vh[e] = hi;
        vl[e] = (_Float16)(v - (float)hi);
    }
    const int idx = ((h*8 + ks)*4 + ob)*64 + lane;
    reinterpret_cast<f16x8*>(wBh)[idx] = vh;
    reinterpret_cast<f16x8*>(wBl)[idx] = vl;
}

// ---------------------------------------------------------------------------
// K1m (v1 — ISOLATION REVERT): Wh = x @ W via MFMA, 3-term double-f16 split.
// Grid 256 = (h, 64-row group); 4 waves x 16 rows; wave = 16 rows x 64 cols
// (4 independent MFMA chains). This exact kernel ran inside R8's 81.0 us.
// ---------------------------------------------------------------------------
__global__ __launch_bounds__(256) void k1m(
    const float* __restrict__ x, const _Float16* __restrict__ wBh,
    const _Float16* __restrict__ wBl, const float* __restrict__ a,
    _Float16* __restrict__ whB, float* __restrict__ s_src,
    float* __restrict__ s_dst, unsigned* __restrict__ smax)
{
    const int b = blockIdx.x;
    const int h = b >> 6, rb = b & 63;
    const int w = threadIdx.x >> 6, lane = threadIdx.x & 63;
    const int row16 = lane & 15, quad = lane >> 4;
    const int n0 = rb*64 + w*16;

    f32x4 acc[4];
#pragma unroll
    for (int ob = 0; ob < 4; ++ob) acc[ob] = (f32x4){0,0,0,0};

    const float* xp = x + (size_t)(n0 + row16)*INF_ + quad*8;
    const f16x8* WH = reinterpret_cast<const f16x8*>(wBh) + (h*8*4)*64 + lane;
    const f16x8* WL = reinterpret_cast<const f16x8*>(wBl) + (h*8*4)*64 + lane;

#pragma unroll
    for (int ks = 0; ks < 8; ++ks) {
        float4 xv0 = *reinterpret_cast<const float4*>(xp + ks*32);
        float4 xv1 = *reinterpret_cast<const float4*>(xp + ks*32 + 4);
        const float xv[8] = {xv0.x,xv0.y,xv0.z,xv0.w,xv1.x,xv1.y,xv1.z,xv1.w};
        f16x8 Ah, Al;
#pragma unroll
        for (int e = 0; e < 8; ++e) {
            _Float16 hi = (_Float16)xv[e];
            Ah[e] = hi;
            Al[e] = (_Float16)(xv[e] - (float)hi);
        }
#pragma unroll
        for (int ob = 0; ob < 4; ++ob) {
            f16x8 bh = WH[(ks*4 + ob)*64];
            f16x8 bl = WL[(ks*4 + ob)*64];
            acc[ob] = __builtin_amdgcn_mfma_f32_16x16x32_f16(Ah, bh, acc[ob], 0, 0, 0);
            acc[ob] = __builtin_amdgcn_mfma_f32_16x16x32_f16(Al, bh, acc[ob], 0, 0, 0);
            acc[ob] = __builtin_amdgcn_mfma_f32_16x16x32_f16(Ah, bl, acc[ob], 0, 0, 0);
        }
    }

    // ---- whB fragment-native store: 8B per ob ----
    {
        const int jblk = n0 >> 5;
        const int qb   = ((n0 & 16) >> 3) + (quad >> 1);
        const int e0   = (quad & 1) * 4;
#pragma unroll
        for (int ob = 0; ob < 4; ++ob) {
            f16x4 st;
#pragma unroll
            for (int q = 0; q < 4; ++q) st[q] = (_Float16)acc[ob][q];
            const size_t off = (((size_t)(h*NGRP + jblk)*4 + ob)*64 + qb*16 + row16)*8 + e0;
            *reinterpret_cast<f16x4*>(whB + off) = st;
        }
    }

    // ---- s_src/s_dst/smax ----
    float asv[4], adv[4];
#pragma unroll
    for (int ob = 0; ob < 4; ++ob) {
        asv[ob] = a[h*128 + ob*16 + row16];
        adv[ob] = a[h*128 + 64 + ob*16 + row16];
    }
    float sq_s[4], sq_d[4];
#pragma unroll
    for (int q = 0; q < 4; ++q) {
        float vs = 0.f, vd = 0.f;
#pragma unroll
        for (int ob = 0; ob < 4; ++ob) {
            vs += acc[ob][q] * asv[ob];
            vd += acc[ob][q] * adv[ob];
        }
#pragma unroll
        for (int m = 1; m <= 8; m <<= 1) {
            vs += __shfl_xor(vs, m);
            vd += __shfl_xor(vd, m);
        }
        sq_s[q] = vs; sq_d[q] = vd;
    }
    if (row16 == 0) {
        float vmax = -3.0e38f;
#pragma unroll
        for (int q = 0; q < 4; ++q) {
            const int n = n0 + quad*4 + q;
            s_src[h*NN + n] = LOG2E * sq_s[q];
            const float sd = LOG2E * sq_d[q];
            s_dst[h*NN + n] = sd;
            vmax = fmaxf(vmax, sd);
        }
        atomicMax(&smax[h], enc_f32(vmax));
    }
}

// ---------------------------------------------------------------------------
// K3: barrier-free fused softmax + P@Wh. Partials packed f16 (cvt_pkrtz).
// ---------------------------------------------------------------------------
template <int USE_PART>
__global__ __launch_bounds__(256, 4) void k3_attn(
    const unsigned* __restrict__ pack, const _Float16* __restrict__ whB,
    const float* __restrict__ s_src, const float* __restrict__ s_dst,
    const unsigned* __restrict__ smax_enc,
    float* __restrict__ outp, float* __restrict__ l_ws)
{
    constexpr int STEPS_ = NN / NSPL / 32;   // 16

    const int b      = blockIdx.x;
    const int jsplit = b % NSPL;
    const int r2     = b / NSPL;
    const int hh     = r2 & 3;
    const int grp    = r2 >> 2;
    const int w      = threadIdx.x >> 6;
    const int lane   = threadIdx.x & 63;
    const int row16  = lane & 15;
    const int quad   = lane >> 4;
    const int i0     = (grp * 4 + w) * 32;
    const int jb0    = jsplit * (NN / NSPL);
    const int jblk0  = jb0 >> 5;

    const float sm = dec_f32(smax_enc[hh]);
    float A1[2], A2[2];
    const unsigned* prow[2];
#pragma unroll
    for (int f = 0; f < 2; ++f) {
        const int ir = i0 + f*16 + row16;
        const float s_i = s_src[hh*NN + ir];
        const float zb  = s_i + sm;
        const float mb  = fmaxf(zb, 0.2f * zb);
        A1[f] = s_i - mb;
        A2[f] = 0.2f * s_i - mb;
        prow[f] = pack + ir*128 + jblk0;
    }

    f32x4 acc[2][4];
    f32x4 accl[2];
#pragma unroll
    for (int f = 0; f < 2; ++f) {
        accl[f] = (f32x4){0,0,0,0};
#pragma unroll
        for (int ob = 0; ob < 4; ++ob) acc[f][ob] = (f32x4){0,0,0,0};
    }

    f16x8 ones;
#pragma unroll
    for (int e = 0; e < 8; ++e) ones[e] = (_Float16)1.0f;

    const _Float16* bB  = whB + (size_t)(hh*NGRP + jblk0)*2048 + lane*8;
    const float*    sdp = s_dst + hh*NN + jb0 + quad*8;

    f16x8 B0 = *reinterpret_cast<const f16x8*>(bB);
    f16x8 B1 = *reinterpret_cast<const f16x8*>(bB + 512);
    f16x8 B2 = *reinterpret_cast<const f16x8*>(bB + 1024);
    f16x8 B3 = *reinterpret_cast<const f16x8*>(bB + 1536);
    unsigned msk0 = prow[0][0], msk1 = prow[1][0];
    float4 sj0 = *reinterpret_cast<const float4*>(sdp);
    float4 sj1 = *reinterpret_cast<const float4*>(sdp + 4);

    for (int s = 0; s < STEPS_; ++s) {
        const _Float16* bn = bB + (s+1)*2048;
        f16x8 nB0 = *reinterpret_cast<const f16x8*>(bn);
        f16x8 nB1 = *reinterpret_cast<const f16x8*>(bn + 512);
        f16x8 nB2 = *reinterpret_cast<const f16x8*>(bn + 1024);
        f16x8 nB3 = *reinterpret_cast<const f16x8*>(bn + 1536);
        unsigned nmsk0 = prow[0][s+1], nmsk1 = prow[1][s+1];
        float4 nsj0 = *reinterpret_cast<const float4*>(sdp + (s+1)*32);
        float4 nsj1 = *reinterpret_cast<const float4*>(sdp + (s+1)*32 + 4);

        const float sjv[8] = {sj0.x,sj0.y,sj0.z,sj0.w,sj1.x,sj1.y,sj1.z,sj1.w};
        float us[8];
#pragma unroll
        for (int e = 0; e < 8; ++e) us[e] = 0.2f * sjv[e];

        const unsigned mskf[2] = {msk0, msk1};
#pragma unroll
        for (int f = 0; f < 2; ++f) {
            const unsigned mm8 = (mskf[f] >> (quad * 8)) & 0xffu;
            float pe[8];
#pragma unroll
            for (int e = 0; e < 8; ++e) {
                float t1 = A1[f] + sjv[e];
                float t2 = A2[f] + us[e];
                float p  = __builtin_amdgcn_exp2f(fmaxf(t1, t2));
                pe[e] = (mm8 & (1u << e)) ? p : 0.0f;
            }
            union { f16x8 v8; fp16x2 p2[4]; } pa;
#pragma unroll
            for (int e2 = 0; e2 < 4; ++e2)
                pa.p2[e2] = __builtin_amdgcn_cvt_pkrtz(pe[2*e2], pe[2*e2+1]);

            acc[f][0] = __builtin_amdgcn_mfma_f32_16x16x32_f16(pa.v8, B0, acc[f][0], 0, 0, 0);
            acc[f][1] = __builtin_amdgcn_mfma_f32_16x16x32_f16(pa.v8, B1, acc[f][1], 0, 0, 0);
            acc[f][2] = __builtin_amdgcn_mfma_f32_16x16x32_f16(pa.v8, B2, acc[f][2], 0, 0, 0);
            acc[f][3] = __builtin_amdgcn_mfma_f32_16x16x32_f16(pa.v8, B3, acc[f][3], 0, 0, 0);
            accl[f]   = __builtin_amdgcn_mfma_f32_16x16x32_f16(pa.v8, ones, accl[f], 0, 0, 0);
        }

        B0 = nB0; B1 = nB1; B2 = nB2; B3 = nB3;
        msk0 = nmsk0; msk1 = nmsk1;
        sj0 = nsj0; sj1 = nsj1;
    }

#pragma unroll
    for (int f = 0; f < 2; ++f) {
        if (row16 == 0) {
#pragma unroll
            for (int q = 0; q < 4; ++q) {
                const int ir = i0 + f*16 + quad*4 + q;
                if (USE_PART) l_ws[(jsplit*NH + hh)*NN + ir] = accl[f][q];
                else          atomicAdd(&l_ws[hh*NN + ir], accl[f][q]);
            }
        }
    }
    if (USE_PART) {
        // packed-f16 wave-native partials: u32 word = (q0,q1) / (q2,q3)
        unsigned* pw = reinterpret_cast<unsigned*>(outp)
                     + ((size_t)((jsplit*NH + hh)*NGRP + (i0 >> 5))) * 1024 + lane;
#pragma unroll
        for (int f = 0; f < 2; ++f)
#pragma unroll
            for (int ob = 0; ob < 4; ++ob) {
                union { fp16x2 h2; unsigned u; } p0, p1;
                p0.h2 = __builtin_amdgcn_cvt_pkrtz(acc[f][ob][0], acc[f][ob][1]);
                p1.h2 = __builtin_amdgcn_cvt_pkrtz(acc[f][ob][2], acc[f][ob][3]);
                pw[((f*4 + ob)*2 + 0)*64] = p0.u;
                pw[((f*4 + ob)*2 + 1)*64] = p1.u;
            }
    } else {
#pragma unroll
        for (int f = 0; f < 2; ++f)
#pragma unroll
            for (int ob = 0; ob < 4; ++ob)
#pragma unroll
                for (int q = 0; q < 4; ++q) {
                    const int grow = i0 + f*16 + quad*4 + q;
                    const int gcol = hh*OUTF + ob*16 + row16;
                    atomicAdd(&outp[(size_t)grow*256 + gcol], acc[f][ob][q]);
                }
    }
}

// ---------------------------------------------------------------------------
// K4 (partials): unscramble packed-f16 partials, out = sum(part)/sum(l)
// ---------------------------------------------------------------------------
__global__ __launch_bounds__(256) void k4_part(const unsigned* __restrict__ part,
                                               const float* __restrict__ l_ws,
                                               float* __restrict__ out)
{
    const int idx = blockIdx.x * 256 + threadIdx.x;   // f32x4 index, < 262144
    const int n = idx >> 6, c4 = idx & 63;
    const int h = c4 >> 4, k = c4 & 15;
    const int g = n >> 5, f = (n >> 4) & 1, quad = (n >> 2) & 3, q = n & 3;
    const int ob = k >> 2, lb = quad*16 + (k & 3)*4;
    const int wi = ((f*4 + ob)*2 + (q >> 1))*64 + lb;
    const int hsel = q & 1;

    float L = 0.f;
    f32x4 v = {0,0,0,0};
#pragma unroll
    for (int sp = 0; sp < NSPL; ++sp) {
        L += l_ws[(sp*NH + h)*NN + n];
        union { uint4 u4; _Float16 hx[8]; } uu;
        uu.u4 = *reinterpret_cast<const uint4*>(part + ((size_t)((sp*NH + h)*NGRP + g))*1024 + wi);
#pragma unroll
        for (int i = 0; i < 4; ++i) v[i] += (float)uu.hx[i*2 + hsel];
    }
    const float inv = 1.0f / L;
    *reinterpret_cast<f32x4*>(out + (size_t)n*256 + c4*4) = v * inv;
}

// K4 (atomic fallback): out /= l
__global__ __launch_bounds__(256) void k4_atomic(float* __restrict__ out,
                                                 const float* __restrict__ l_acc)
{
    const int idx = blockIdx.x * 256 + threadIdx.x;
    const int n = idx >> 6, c4 = idx & 63, h = c4 >> 4;
    const float inv = 1.0f / l_acc[h*NN + n];
    f32x4 v = *reinterpret_cast<f32x4*>(out + (size_t)n*256 + c4*4);
    *reinterpret_cast<f32x4*>(out + (size_t)n*256 + c4*4) = v * inv;
}

extern "C" void kernel_launch(void* const* d_in, const int* in_sizes, int n_in,
                              void* d_out, int out_size, void* d_ws, size_t ws_size,
                              hipStream_t stream)
{
    const float* x   = (const float*)d_in[0];
    const float* adj = (const float*)d_in[1];
    const float* W   = (const float*)d_in[2];
    const float* a   = (const float*)d_in[3];
    float* out = (float*)d_out;

    char* ws = (char*)d_ws;
    _Float16* whB  = (_Float16*)ws;                              // 2 MB
    unsigned* pack = (unsigned*)(ws + (2u<<20));                 // 2 MB
    _Float16* wBh  = (_Float16*)(ws + (4u<<20));                 // 128 KB
    _Float16* wBl  = (_Float16*)(ws + (4u<<20) + (128u<<10));    // 128 KB
    float* s_src   = (float*)(ws + (4u<<20) + (256u<<10));       // 64 KB
    float* s_dst   = (float*)(ws + (4u<<20) + (320u<<10));       // 64 KB
    unsigned* smax = (unsigned*)(ws + (4u<<20) + (384u<<10));    // 1 KB slot
    float* l_ws    = (float*)(ws + (4u<<20) + (385u<<10));       // 512 KB
    char*  partb   = ws + (4u<<20) + (897u<<10);                 // 16 MB (f16-packed)

    const size_t need = (4u<<20) + (897u<<10) + (size_t)NSPL * NN * 256 * 2;

    k0_pack<<<NN, 256, 0, stream>>>(adj, pack, smax);
    kW_tr  <<<32, 256, 0, stream>>>(W, wBh, wBl);
    k1m    <<<256, 256, 0, stream>>>(x, wBh, wBl, a, whB, s_src, s_dst, smax);

    if (ws_size >= need) {
        k3_attn<1><<<1024, 256, 0, stream>>>(pack, whB, s_src, s_dst, smax,
                                             (float*)partb, l_ws);
        k4_part<<<1024, 256, 0, stream>>>((const unsigned*)partb, l_ws, out);
    } else {
        (void)hipMemsetAsync(d_out, 0, (size_t)out_size * sizeof(float), stream);
        (void)hipMemsetAsync(l_ws, 0, NH * NN * sizeof(float), stream);
        k3_attn<0><<<1024, 256, 0, stream>>>(pack, whB, s_src, s_dst, smax, out, l_ws);
        k4_atomic<<<1024, 256, 0, stream>>>(out, l_ws);
    }
}

// Round 12
// 81.595 us; speedup vs baseline: 1.2467x; 1.1983x over previous
//
#include <hip/hip_runtime.h>
#include <hip/hip_bf16.h>

typedef float    f32x4 __attribute__((ext_vector_type(4)));
typedef _Float16 f16x8 __attribute__((ext_vector_type(8)));
typedef _Float16 f16x4 __attribute__((ext_vector_type(4)));
typedef __fp16   fp16x2 __attribute__((ext_vector_type(2)));

#define NN 4096
#define INF_ 256
#define OUTF 64
#define NH 4
#define NSPL 8
#define NGRP 128            // NN/32
#define LOG2E 1.4426950408889634f

// ---------------------------------------------------------------------------
// K0: pack adj (0/1 floats) into bitmask; diagonal forced 1; init smax.
// ---------------------------------------------------------------------------
__global__ __launch_bounds__(256) void k0_pack(const float* __restrict__ adj,
                                               unsigned* __restrict__ pack,
                                               unsigned* __restrict__ smax)
{
    const int r    = blockIdx.x;
    const int w    = threadIdx.x >> 6;
    const int lane = threadIdx.x & 63;
    const float* row = adj + (size_t)r * NN + w * 1024;
#pragma unroll
    for (int i = 0; i < 4; ++i) {
        float a0 = row[i*256 + lane];
        float a1 = row[i*256 +  64 + lane];
        float a2 = row[i*256 + 128 + lane];
        float a3 = row[i*256 + 192 + lane];
        unsigned long long bal[4];
        bal[0] = __ballot(a0 != 0.f);
        bal[1] = __ballot(a1 != 0.f);
        bal[2] = __ballot(a2 != 0.f);
        bal[3] = __ballot(a3 != 0.f);
        if (lane < 2) {
#pragma unroll
            for (int k = 0; k < 4; ++k) {
                int wi = w*32 + i*8 + k*2 + lane;
                unsigned v = (unsigned)(bal[k] >> (lane * 32));
                if (wi == (r >> 5)) v |= 1u << (r & 31);   // diagonal
                pack[r*128 + wi] = v;
            }
        }
    }
    if (r == 0 && threadIdx.x < NH) smax[threadIdx.x] = 0u;
}

__device__ __forceinline__ unsigned enc_f32(float f) {
    unsigned u = __float_as_uint(f);
    return (u & 0x80000000u) ? ~u : (u | 0x80000000u);
}
__device__ __forceinline__ float dec_f32(unsigned u) {
    return (u & 0x80000000u) ? __uint_as_float(u ^ 0x80000000u)
                             : __uint_as_float(~u);
}

// ---------------------------------------------------------------------------
// KW: transpose W into MFMA-B fragment-native f16, split hi/lo.
// ---------------------------------------------------------------------------
__global__ __launch_bounds__(256) void kW_tr(const float* __restrict__ W,
                                             _Float16* __restrict__ wBh,
                                             _Float16* __restrict__ wBl)
{
    const int b = blockIdx.x;
    const int h = b >> 3, ks = b & 7;
    const int t = threadIdx.x;
    const int ob = t >> 6, lane = t & 63;
    const int row16 = lane & 15, quad = lane >> 4;

    const float* wp = W + (size_t)h*INF_*OUTF + (ks*32 + quad*8)*OUTF + ob*16 + row16;
    f16x8 vh, vl;
#pragma unroll
    for (int e = 0; e < 8; ++e) {
        float v = wp[e*OUTF];
        _Float16 hi = (_Float16)v;
        vh[e] = hi;
        vl[e] = (_Float16)(v - (float)hi);
    }
    const int idx = ((h*8 + ks)*4 + ob)*64 + lane;
    reinterpret_cast<f16x8*>(wBh)[idx] = vh;
    reinterpret_cast<f16x8*>(wBl)[idx] = vl;
}

// ---------------------------------------------------------------------------
// K1m (v1 + 3-acc ILP): Wh = x @ W via MFMA, 3-term double-f16 split.
// Grid 256 = (h, 64-row group); 4 waves x 16 rows; wave = 16 rows x 64 cols.
// Each of the 3 split terms gets its OWN accumulator -> 12 independent
// MFMA chains of length 8 (v1 had 4 chains of 24 -> latency-bound).
// Summed at the end (pure f32 reassociation).
// ---------------------------------------------------------------------------
__global__ __launch_bounds__(256) void k1m(
    const float* __restrict__ x, const _Float16* __restrict__ wBh,
    const _Float16* __restrict__ wBl, const float* __restrict__ a,
    _Float16* __restrict__ whB, float* __restrict__ s_src,
    float* __restrict__ s_dst, unsigned* __restrict__ smax)
{
    const int b = blockIdx.x;
    const int h = b >> 6, rb = b & 63;
    const int w = threadIdx.x >> 6, lane = threadIdx.x & 63;
    const int row16 = lane & 15, quad = lane >> 4;
    const int n0 = rb*64 + w*16;

    f32x4 accA[4], accB[4], accC[4];
#pragma unroll
    for (int ob = 0; ob < 4; ++ob) {
        accA[ob] = (f32x4){0,0,0,0};
        accB[ob] = (f32x4){0,0,0,0};
        accC[ob] = (f32x4){0,0,0,0};
    }

    const float* xp = x + (size_t)(n0 + row16)*INF_ + quad*8;
    const f16x8* WH = reinterpret_cast<const f16x8*>(wBh) + (h*8*4)*64 + lane;
    const f16x8* WL = reinterpret_cast<const f16x8*>(wBl) + (h*8*4)*64 + lane;

#pragma unroll
    for (int ks = 0; ks < 8; ++ks) {
        float4 xv0 = *reinterpret_cast<const float4*>(xp + ks*32);
        float4 xv1 = *reinterpret_cast<const float4*>(xp + ks*32 + 4);
        const float xv[8] = {xv0.x,xv0.y,xv0.z,xv0.w,xv1.x,xv1.y,xv1.z,xv1.w};
        f16x8 Ah, Al;
#pragma unroll
        for (int e = 0; e < 8; ++e) {
            _Float16 hi = (_Float16)xv[e];
            Ah[e] = hi;
            Al[e] = (_Float16)(xv[e] - (float)hi);
        }
#pragma unroll
        for (int ob = 0; ob < 4; ++ob) {
            f16x8 bh = WH[(ks*4 + ob)*64];
            f16x8 bl = WL[(ks*4 + ob)*64];
            accA[ob] = __builtin_amdgcn_mfma_f32_16x16x32_f16(Ah, bh, accA[ob], 0, 0, 0);
            accB[ob] = __builtin_amdgcn_mfma_f32_16x16x32_f16(Al, bh, accB[ob], 0, 0, 0);
            accC[ob] = __builtin_amdgcn_mfma_f32_16x16x32_f16(Ah, bl, accC[ob], 0, 0, 0);
        }
    }

    f32x4 acc[4];
#pragma unroll
    for (int ob = 0; ob < 4; ++ob)
        acc[ob] = accA[ob] + accB[ob] + accC[ob];

    // ---- whB fragment-native store: 8B per ob ----
    {
        const int jblk = n0 >> 5;
        const int qb   = ((n0 & 16) >> 3) + (quad >> 1);
        const int e0   = (quad & 1) * 4;
#pragma unroll
        for (int ob = 0; ob < 4; ++ob) {
            f16x4 st;
#pragma unroll
            for (int q = 0; q < 4; ++q) st[q] = (_Float16)acc[ob][q];
            const size_t off = (((size_t)(h*NGRP + jblk)*4 + ob)*64 + qb*16 + row16)*8 + e0;
            *reinterpret_cast<f16x4*>(whB + off) = st;
        }
    }

    // ---- s_src/s_dst/smax ----
    float asv[4], adv[4];
#pragma unroll
    for (int ob = 0; ob < 4; ++ob) {
        asv[ob] = a[h*128 + ob*16 + row16];
        adv[ob] = a[h*128 + 64 + ob*16 + row16];
    }
    float sq_s[4], sq_d[4];
#pragma unroll
    for (int q = 0; q < 4; ++q) {
        float vs = 0.f, vd = 0.f;
#pragma unroll
        for (int ob = 0; ob < 4; ++ob) {
            vs += acc[ob][q] * asv[ob];
            vd += acc[ob][q] * adv[ob];
        }
#pragma unroll
        for (int m = 1; m <= 8; m <<= 1) {
            vs += __shfl_xor(vs, m);
            vd += __shfl_xor(vd, m);
        }
        sq_s[q] = vs; sq_d[q] = vd;
    }
    if (row16 == 0) {
        float vmax = -3.0e38f;
#pragma unroll
        for (int q = 0; q < 4; ++q) {
            const int n = n0 + quad*4 + q;
            s_src[h*NN + n] = LOG2E * sq_s[q];
            const float sd = LOG2E * sq_d[q];
            s_dst[h*NN + n] = sd;
            vmax = fmaxf(vmax, sd);
        }
        atomicMax(&smax[h], enc_f32(vmax));
    }
}

// ---------------------------------------------------------------------------
// K3: barrier-free fused softmax + P@Wh. f32 wave-native partials
// (f16-packed partials measured +16.8 us — reverted, R10 isolation).
// ---------------------------------------------------------------------------
template <int USE_PART>
__global__ __launch_bounds__(256, 4) void k3_attn(
    const unsigned* __restrict__ pack, const _Float16* __restrict__ whB,
    const float* __restrict__ s_src, const float* __restrict__ s_dst,
    const unsigned* __restrict__ smax_enc,
    float* __restrict__ outp, float* __restrict__ l_ws)
{
    constexpr int STEPS_ = NN / NSPL / 32;   // 16

    const int b      = blockIdx.x;
    const int jsplit = b % NSPL;
    const int r2     = b / NSPL;
    const int hh     = r2 & 3;
    const int grp    = r2 >> 2;
    const int w      = threadIdx.x >> 6;
    const int lane   = threadIdx.x & 63;
    const int row16  = lane & 15;
    const int quad   = lane >> 4;
    const int i0     = (grp * 4 + w) * 32;
    const int jb0    = jsplit * (NN / NSPL);
    const int jblk0  = jb0 >> 5;

    const float sm = dec_f32(smax_enc[hh]);
    float A1[2], A2[2];
    const unsigned* prow[2];
#pragma unroll
    for (int f = 0; f < 2; ++f) {
        const int ir = i0 + f*16 + row16;
        const float s_i = s_src[hh*NN + ir];
        const float zb  = s_i + sm;
        const float mb  = fmaxf(zb, 0.2f * zb);
        A1[f] = s_i - mb;
        A2[f] = 0.2f * s_i - mb;
        prow[f] = pack + ir*128 + jblk0;
    }

    f32x4 acc[2][4];
    f32x4 accl[2];
#pragma unroll
    for (int f = 0; f < 2; ++f) {
        accl[f] = (f32x4){0,0,0,0};
#pragma unroll
        for (int ob = 0; ob < 4; ++ob) acc[f][ob] = (f32x4){0,0,0,0};
    }

    f16x8 ones;
#pragma unroll
    for (int e = 0; e < 8; ++e) ones[e] = (_Float16)1.0f;

    const _Float16* bB  = whB + (size_t)(hh*NGRP + jblk0)*2048 + lane*8;
    const float*    sdp = s_dst + hh*NN + jb0 + quad*8;

    f16x8 B0 = *reinterpret_cast<const f16x8*>(bB);
    f16x8 B1 = *reinterpret_cast<const f16x8*>(bB + 512);
    f16x8 B2 = *reinterpret_cast<const f16x8*>(bB + 1024);
    f16x8 B3 = *reinterpret_cast<const f16x8*>(bB + 1536);
    unsigned msk0 = prow[0][0], msk1 = prow[1][0];
    float4 sj0 = *reinterpret_cast<const float4*>(sdp);
    float4 sj1 = *reinterpret_cast<const float4*>(sdp + 4);

    for (int s = 0; s < STEPS_; ++s) {
        const _Float16* bn = bB + (s+1)*2048;
        f16x8 nB0 = *reinterpret_cast<const f16x8*>(bn);
        f16x8 nB1 = *reinterpret_cast<const f16x8*>(bn + 512);
        f16x8 nB2 = *reinterpret_cast<const f16x8*>(bn + 1024);
        f16x8 nB3 = *reinterpret_cast<const f16x8*>(bn + 1536);
        unsigned nmsk0 = prow[0][s+1], nmsk1 = prow[1][s+1];
        float4 nsj0 = *reinterpret_cast<const float4*>(sdp + (s+1)*32);
        float4 nsj1 = *reinterpret_cast<const float4*>(sdp + (s+1)*32 + 4);

        const float sjv[8] = {sj0.x,sj0.y,sj0.z,sj0.w,sj1.x,sj1.y,sj1.z,sj1.w};
        float us[8];
#pragma unroll
        for (int e = 0; e < 8; ++e) us[e] = 0.2f * sjv[e];

        const unsigned mskf[2] = {msk0, msk1};
#pragma unroll
        for (int f = 0; f < 2; ++f) {
            const unsigned mm8 = (mskf[f] >> (quad * 8)) & 0xffu;
            float pe[8];
#pragma unroll
            for (int e = 0; e < 8; ++e) {
                float t1 = A1[f] + sjv[e];
                float t2 = A2[f] + us[e];
                float p  = __builtin_amdgcn_exp2f(fmaxf(t1, t2));
                pe[e] = (mm8 & (1u << e)) ? p : 0.0f;
            }
            union { f16x8 v8; fp16x2 p2[4]; } pa;
#pragma unroll
            for (int e2 = 0; e2 < 4; ++e2)
                pa.p2[e2] = __builtin_amdgcn_cvt_pkrtz(pe[2*e2], pe[2*e2+1]);

            acc[f][0] = __builtin_amdgcn_mfma_f32_16x16x32_f16(pa.v8, B0, acc[f][0], 0, 0, 0);
            acc[f][1] = __builtin_amdgcn_mfma_f32_16x16x32_f16(pa.v8, B1, acc[f][1], 0, 0, 0);
            acc[f][2] = __builtin_amdgcn_mfma_f32_16x16x32_f16(pa.v8, B2, acc[f][2], 0, 0, 0);
            acc[f][3] = __builtin_amdgcn_mfma_f32_16x16x32_f16(pa.v8, B3, acc[f][3], 0, 0, 0);
            accl[f]   = __builtin_amdgcn_mfma_f32_16x16x32_f16(pa.v8, ones, accl[f], 0, 0, 0);
        }

        B0 = nB0; B1 = nB1; B2 = nB2; B3 = nB3;
        msk0 = nmsk0; msk1 = nmsk1;
        sj0 = nsj0; sj1 = nsj1;
    }

#pragma unroll
    for (int f = 0; f < 2; ++f) {
        if (row16 == 0) {
#pragma unroll
            for (int q = 0; q < 4; ++q) {
                const int ir = i0 + f*16 + quad*4 + q;
                if (USE_PART) l_ws[(jsplit*NH + hh)*NN + ir] = accl[f][q];
                else          atomicAdd(&l_ws[hh*NN + ir], accl[f][q]);
            }
        }
    }
    if (USE_PART) {
        // f32 wave-native partials: 256B coalesced stores
        float* pw = outp + ((size_t)((jsplit*NH + hh)*NGRP + (i0 >> 5))) * 2048 + lane;
#pragma unroll
        for (int f = 0; f < 2; ++f)
#pragma unroll
            for (int ob = 0; ob < 4; ++ob)
#pragma unroll
                for (int q = 0; q < 4; ++q)
                    pw[((f*4 + ob)*4 + q)*64] = acc[f][ob][q];
    } else {
#pragma unroll
        for (int f = 0; f < 2; ++f)
#pragma unroll
            for (int ob = 0; ob < 4; ++ob)
#pragma unroll
                for (int q = 0; q < 4; ++q) {
                    const int grow = i0 + f*16 + quad*4 + q;
                    const int gcol = hh*OUTF + ob*16 + row16;
                    atomicAdd(&outp[(size_t)grow*256 + gcol], acc[f][ob][q]);
                }
    }
}

// ---------------------------------------------------------------------------
// K4 (partials): unscramble f32 wave-native partials, out = sum/sum(l)
// ---------------------------------------------------------------------------
__global__ __launch_bounds__(256) void k4_part(const float* __restrict__ part,
                                               const float* __restrict__ l_ws,
                                               float* __restrict__ out)
{
    const int idx = blockIdx.x * 256 + threadIdx.x;   // f32x4 index, < 262144
    const int n = idx >> 6, c4 = idx & 63;
    const int h = c4 >> 4, k = c4 & 15;
    const int g = n >> 5, f = (n >> 4) & 1, quad = (n >> 2) & 3, q = n & 3;
    const int ob = k >> 2, lb = quad*16 + (k & 3)*4;

    float L = 0.f;
    f32x4 v = {0,0,0,0};
#pragma unroll
    for (int sp = 0; sp < NSPL; ++sp) {
        L += l_ws[(sp*NH + h)*NN + n];
        const float* p = part + ((size_t)((sp*NH + h)*NGRP + g))*2048
                              + ((f*4 + ob)*4 + q)*64 + lb;
        v += *reinterpret_cast<const f32x4*>(p);
    }
    const float inv = 1.0f / L;
    *reinterpret_cast<f32x4*>(out + (size_t)n*256 + c4*4) = v * inv;
}

// K4 (atomic fallback): out /= l
__global__ __launch_bounds__(256) void k4_atomic(float* __restrict__ out,
                                                 const float* __restrict__ l_acc)
{
    const int idx = blockIdx.x * 256 + threadIdx.x;
    const int n = idx >> 6, c4 = idx & 63, h = c4 >> 4;
    const float inv = 1.0f / l_acc[h*NN + n];
    f32x4 v = *reinterpret_cast<f32x4*>(out + (size_t)n*256 + c4*4);
    *reinterpret_cast<f32x4*>(out + (size_t)n*256 + c4*4) = v * inv;
}

extern "C" void kernel_launch(void* const* d_in, const int* in_sizes, int n_in,
                              void* d_out, int out_size, void* d_ws, size_t ws_size,
                              hipStream_t stream)
{
    const float* x   = (const float*)d_in[0];
    const float* adj = (const float*)d_in[1];
    const float* W   = (const float*)d_in[2];
    const float* a   = (const float*)d_in[3];
    float* out = (float*)d_out;

    char* ws = (char*)d_ws;
    _Float16* whB  = (_Float16*)ws;                              // 2 MB
    unsigned* pack = (unsigned*)(ws + (2u<<20));                 // 2 MB
    _Float16* wBh  = (_Float16*)(ws + (4u<<20));                 // 128 KB
    _Float16* wBl  = (_Float16*)(ws + (4u<<20) + (128u<<10));    // 128 KB
    float* s_src   = (float*)(ws + (4u<<20) + (256u<<10));       // 64 KB
    float* s_dst   = (float*)(ws + (4u<<20) + (320u<<10));       // 64 KB
    unsigned* smax = (unsigned*)(ws + (4u<<20) + (384u<<10));    // 1 KB slot
    float* l_ws    = (float*)(ws + (4u<<20) + (385u<<10));       // 512 KB
    float* part    = (float*)(ws + (4u<<20) + (897u<<10));       // 32 MB (f32)

    const size_t need = (4u<<20) + (897u<<10) + (size_t)NSPL * NN * 256 * 4;

    k0_pack<<<NN, 256, 0, stream>>>(adj, pack, smax);
    kW_tr  <<<32, 256, 0, stream>>>(W, wBh, wBl);
    k1m    <<<256, 256, 0, stream>>>(x, wBh, wBl, a, whB, s_src, s_dst, smax);

    if (ws_size >= need) {
        k3_attn<1><<<1024, 256, 0, stream>>>(pack, whB, s_src, s_dst, smax, part, l_ws);
        k4_part<<<1024, 256, 0, stream>>>(part, l_ws, out);
    } else {
        (void)hipMemsetAsync(d_out, 0, (size_t)out_size * sizeof(float), stream);
        (void)hipMemsetAsync(l_ws, 0, NH * NN * sizeof(float), stream);
        k3_attn<0><<<1024, 256, 0, stream>>>(pack, whB, s_src, s_dst, smax, out, l_ws);
        k4_atomic<<<1024, 256, 0, stream>>>(out, l_ws);
    }
}

// Round 13
// 78.241 us; speedup vs baseline: 1.3001x; 1.0429x over previous
//
#include <hip/hip_runtime.h>
#include <hip/hip_bf16.h>

typedef float    f32x4 __attribute__((ext_vector_type(4)));
typedef _Float16 f16x8 __attribute__((ext_vector_type(8)));
typedef _Float16 f16x4 __attribute__((ext_vector_type(4)));
typedef __fp16   fp16x2 __attribute__((ext_vector_type(2)));

#define NN 4096
#define INF_ 256
#define OUTF 64
#define NH 4
#define NSPL 8
#define NGRP 128            // NN/32
#define LOG2E 1.4426950408889634f

__device__ __forceinline__ unsigned enc_f32(float f) {
    unsigned u = __float_as_uint(f);
    return (u & 0x80000000u) ? ~u : (u | 0x80000000u);
}
__device__ __forceinline__ float dec_f32(unsigned u) {
    return (u & 0x80000000u) ? __uint_as_float(u ^ 0x80000000u)
                             : __uint_as_float(~u);
}

// ---------------------------------------------------------------------------
// KW: transpose W into MFMA-B fragment-native f16, split hi/lo. Inits smax.
// ---------------------------------------------------------------------------
__global__ __launch_bounds__(256) void kW_tr(const float* __restrict__ W,
                                             _Float16* __restrict__ wBh,
                                             _Float16* __restrict__ wBl,
                                             unsigned* __restrict__ smax)
{
    const int b = blockIdx.x;
    const int h = b >> 3, ks = b & 7;
    const int t = threadIdx.x;
    const int ob = t >> 6, lane = t & 63;
    const int row16 = lane & 15, quad = lane >> 4;

    const float* wp = W + (size_t)h*INF_*OUTF + (ks*32 + quad*8)*OUTF + ob*16 + row16;
    f16x8 vh, vl;
#pragma unroll
    for (int e = 0; e < 8; ++e) {
        float v = wp[e*OUTF];
        _Float16 hi = (_Float16)v;
        vh[e] = hi;
        vl[e] = (_Float16)(v - (float)hi);
    }
    const int idx = ((h*8 + ks)*4 + ob)*64 + lane;
    reinterpret_cast<f16x8*>(wBh)[idx] = vh;
    reinterpret_cast<f16x8*>(wBl)[idx] = vl;

    if (b == 0 && t < NH) smax[t] = 0u;   // moved from k0 (k01 merge)
}

// ---------------------------------------------------------------------------
// K01: merged k1m || k0 (data-independent -> co-scheduled in one dispatch;
// k1m's latency hides under k0's HBM streaming).
// Blocks 0..255: k1m (Wh = x@W, 3-term double-f16 MFMA; whB fragment-
// native store; s_src/s_dst; smax atomicMax).
// Blocks 256..4351: k0 (pack adj row into bitmask, diagonal forced 1).
// ---------------------------------------------------------------------------
__global__ __launch_bounds__(256) void k01(
    const float* __restrict__ adj, unsigned* __restrict__ pack,
    const float* __restrict__ x, const _Float16* __restrict__ wBh,
    const _Float16* __restrict__ wBl, const float* __restrict__ a,
    _Float16* __restrict__ whB, float* __restrict__ s_src,
    float* __restrict__ s_dst, unsigned* __restrict__ smax)
{
    if (blockIdx.x >= 256) {
        // ---------------- k0: adj bitmask pack ----------------
        const int r    = blockIdx.x - 256;
        const int w    = threadIdx.x >> 6;
        const int lane = threadIdx.x & 63;
        const float* row = adj + (size_t)r * NN + w * 1024;
#pragma unroll
        for (int i = 0; i < 4; ++i) {
            float a0 = row[i*256 + lane];
            float a1 = row[i*256 +  64 + lane];
            float a2 = row[i*256 + 128 + lane];
            float a3 = row[i*256 + 192 + lane];
            unsigned long long bal[4];
            bal[0] = __ballot(a0 != 0.f);
            bal[1] = __ballot(a1 != 0.f);
            bal[2] = __ballot(a2 != 0.f);
            bal[3] = __ballot(a3 != 0.f);
            if (lane < 2) {
#pragma unroll
                for (int k = 0; k < 4; ++k) {
                    int wi = w*32 + i*8 + k*2 + lane;
                    unsigned v = (unsigned)(bal[k] >> (lane * 32));
                    if (wi == (r >> 5)) v |= 1u << (r & 31);   // diagonal
                    pack[r*128 + wi] = v;
                }
            }
        }
        return;
    }

    // ---------------- k1m: Wh = x @ W ----------------
    const int b = blockIdx.x;
    const int h = b >> 6, rb = b & 63;
    const int w = threadIdx.x >> 6, lane = threadIdx.x & 63;
    const int row16 = lane & 15, quad = lane >> 4;
    const int n0 = rb*64 + w*16;

    f32x4 accA[4], accB[4], accC[4];
#pragma unroll
    for (int ob = 0; ob < 4; ++ob) {
        accA[ob] = (f32x4){0,0,0,0};
        accB[ob] = (f32x4){0,0,0,0};
        accC[ob] = (f32x4){0,0,0,0};
    }

    const float* xp = x + (size_t)(n0 + row16)*INF_ + quad*8;
    const f16x8* WH = reinterpret_cast<const f16x8*>(wBh) + (h*8*4)*64 + lane;
    const f16x8* WL = reinterpret_cast<const f16x8*>(wBl) + (h*8*4)*64 + lane;

#pragma unroll
    for (int ks = 0; ks < 8; ++ks) {
        float4 xv0 = *reinterpret_cast<const float4*>(xp + ks*32);
        float4 xv1 = *reinterpret_cast<const float4*>(xp + ks*32 + 4);
        const float xv[8] = {xv0.x,xv0.y,xv0.z,xv0.w,xv1.x,xv1.y,xv1.z,xv1.w};
        f16x8 Ah, Al;
#pragma unroll
        for (int e = 0; e < 8; ++e) {
            _Float16 hi = (_Float16)xv[e];
            Ah[e] = hi;
            Al[e] = (_Float16)(xv[e] - (float)hi);
        }
#pragma unroll
        for (int ob = 0; ob < 4; ++ob) {
            f16x8 bh = WH[(ks*4 + ob)*64];
            f16x8 bl = WL[(ks*4 + ob)*64];
            accA[ob] = __builtin_amdgcn_mfma_f32_16x16x32_f16(Ah, bh, accA[ob], 0, 0, 0);
            accB[ob] = __builtin_amdgcn_mfma_f32_16x16x32_f16(Al, bh, accB[ob], 0, 0, 0);
            accC[ob] = __builtin_amdgcn_mfma_f32_16x16x32_f16(Ah, bl, accC[ob], 0, 0, 0);
        }
    }

    f32x4 acc[4];
#pragma unroll
    for (int ob = 0; ob < 4; ++ob)
        acc[ob] = accA[ob] + accB[ob] + accC[ob];

    // ---- whB fragment-native store: 8B per ob ----
    {
        const int jblk = n0 >> 5;
        const int qb   = ((n0 & 16) >> 3) + (quad >> 1);
        const int e0   = (quad & 1) * 4;
#pragma unroll
        for (int ob = 0; ob < 4; ++ob) {
            f16x4 st;
#pragma unroll
            for (int q = 0; q < 4; ++q) st[q] = (_Float16)acc[ob][q];
            const size_t off = (((size_t)(h*NGRP + jblk)*4 + ob)*64 + qb*16 + row16)*8 + e0;
            *reinterpret_cast<f16x4*>(whB + off) = st;
        }
    }

    // ---- s_src/s_dst/smax ----
    float asv[4], adv[4];
#pragma unroll
    for (int ob = 0; ob < 4; ++ob) {
        asv[ob] = a[h*128 + ob*16 + row16];
        adv[ob] = a[h*128 + 64 + ob*16 + row16];
    }
    float sq_s[4], sq_d[4];
#pragma unroll
    for (int q = 0; q < 4; ++q) {
        float vs = 0.f, vd = 0.f;
#pragma unroll
        for (int ob = 0; ob < 4; ++ob) {
            vs += acc[ob][q] * asv[ob];
            vd += acc[ob][q] * adv[ob];
        }
#pragma unroll
        for (int m = 1; m <= 8; m <<= 1) {
            vs += __shfl_xor(vs, m);
            vd += __shfl_xor(vd, m);
        }
        sq_s[q] = vs; sq_d[q] = vd;
    }
    if (row16 == 0) {
        float vmax = -3.0e38f;
#pragma unroll
        for (int q = 0; q < 4; ++q) {
            const int n = n0 + quad*4 + q;
            s_src[h*NN + n] = LOG2E * sq_s[q];
            const float sd = LOG2E * sq_d[q];
            s_dst[h*NN + n] = sd;
            vmax = fmaxf(vmax, sd);
        }
        atomicMax(&smax[h], enc_f32(vmax));
    }
}

// ---------------------------------------------------------------------------
// K3: barrier-free fused softmax + P@Wh. f32 wave-native partials
// (f16-packed partials measured +16.8 us — stays f32, R10 isolation).
// ---------------------------------------------------------------------------
template <int USE_PART>
__global__ __launch_bounds__(256, 4) void k3_attn(
    const unsigned* __restrict__ pack, const _Float16* __restrict__ whB,
    const float* __restrict__ s_src, const float* __restrict__ s_dst,
    const unsigned* __restrict__ smax_enc,
    float* __restrict__ outp, float* __restrict__ l_ws)
{
    constexpr int STEPS_ = NN / NSPL / 32;   // 16

    const int b      = blockIdx.x;
    const int jsplit = b % NSPL;
    const int r2     = b / NSPL;
    const int hh     = r2 & 3;
    const int grp    = r2 >> 2;
    const int w      = threadIdx.x >> 6;
    const int lane   = threadIdx.x & 63;
    const int row16  = lane & 15;
    const int quad   = lane >> 4;
    const int i0     = (grp * 4 + w) * 32;
    const int jb0    = jsplit * (NN / NSPL);
    const int jblk0  = jb0 >> 5;

    const float sm = dec_f32(smax_enc[hh]);
    float A1[2], A2[2];
    const unsigned* prow[2];
#pragma unroll
    for (int f = 0; f < 2; ++f) {
        const int ir = i0 + f*16 + row16;
        const float s_i = s_src[hh*NN + ir];
        const float zb  = s_i + sm;
        const float mb  = fmaxf(zb, 0.2f * zb);
        A1[f] = s_i - mb;
        A2[f] = 0.2f * s_i - mb;
        prow[f] = pack + ir*128 + jblk0;
    }

    f32x4 acc[2][4];
    f32x4 accl[2];
#pragma unroll
    for (int f = 0; f < 2; ++f) {
        accl[f] = (f32x4){0,0,0,0};
#pragma unroll
        for (int ob = 0; ob < 4; ++ob) acc[f][ob] = (f32x4){0,0,0,0};
    }

    f16x8 ones;
#pragma unroll
    for (int e = 0; e < 8; ++e) ones[e] = (_Float16)1.0f;

    const _Float16* bB  = whB + (size_t)(hh*NGRP + jblk0)*2048 + lane*8;
    const float*    sdp = s_dst + hh*NN + jb0 + quad*8;

    f16x8 B0 = *reinterpret_cast<const f16x8*>(bB);
    f16x8 B1 = *reinterpret_cast<const f16x8*>(bB + 512);
    f16x8 B2 = *reinterpret_cast<const f16x8*>(bB + 1024);
    f16x8 B3 = *reinterpret_cast<const f16x8*>(bB + 1536);
    unsigned msk0 = prow[0][0], msk1 = prow[1][0];
    float4 sj0 = *reinterpret_cast<const float4*>(sdp);
    float4 sj1 = *reinterpret_cast<const float4*>(sdp + 4);

    for (int s = 0; s < STEPS_; ++s) {
        const _Float16* bn = bB + (s+1)*2048;
        f16x8 nB0 = *reinterpret_cast<const f16x8*>(bn);
        f16x8 nB1 = *reinterpret_cast<const f16x8*>(bn + 512);
        f16x8 nB2 = *reinterpret_cast<const f16x8*>(bn + 1024);
        f16x8 nB3 = *reinterpret_cast<const f16x8*>(bn + 1536);
        unsigned nmsk0 = prow[0][s+1], nmsk1 = prow[1][s+1];
        float4 nsj0 = *reinterpret_cast<const float4*>(sdp + (s+1)*32);
        float4 nsj1 = *reinterpret_cast<const float4*>(sdp + (s+1)*32 + 4);

        const float sjv[8] = {sj0.x,sj0.y,sj0.z,sj0.w,sj1.x,sj1.y,sj1.z,sj1.w};
        float us[8];
#pragma unroll
        for (int e = 0; e < 8; ++e) us[e] = 0.2f * sjv[e];

        const unsigned mskf[2] = {msk0, msk1};
#pragma unroll
        for (int f = 0; f < 2; ++f) {
            const unsigned mm8 = (mskf[f] >> (quad * 8)) & 0xffu;
            float pe[8];
#pragma unroll
            for (int e = 0; e < 8; ++e) {
                float t1 = A1[f] + sjv[e];
                float t2 = A2[f] + us[e];
                float p  = __builtin_amdgcn_exp2f(fmaxf(t1, t2));
                pe[e] = (mm8 & (1u << e)) ? p : 0.0f;
            }
            union { f16x8 v8; fp16x2 p2[4]; } pa;
#pragma unroll
            for (int e2 = 0; e2 < 4; ++e2)
                pa.p2[e2] = __builtin_amdgcn_cvt_pkrtz(pe[2*e2], pe[2*e2+1]);

            acc[f][0] = __builtin_amdgcn_mfma_f32_16x16x32_f16(pa.v8, B0, acc[f][0], 0, 0, 0);
            acc[f][1] = __builtin_amdgcn_mfma_f32_16x16x32_f16(pa.v8, B1, acc[f][1], 0, 0, 0);
            acc[f][2] = __builtin_amdgcn_mfma_f32_16x16x32_f16(pa.v8, B2, acc[f][2], 0, 0, 0);
            acc[f][3] = __builtin_amdgcn_mfma_f32_16x16x32_f16(pa.v8, B3, acc[f][3], 0, 0, 0);
            accl[f]   = __builtin_amdgcn_mfma_f32_16x16x32_f16(pa.v8, ones, accl[f], 0, 0, 0);
        }

        B0 = nB0; B1 = nB1; B2 = nB2; B3 = nB3;
        msk0 = nmsk0; msk1 = nmsk1;
        sj0 = nsj0; sj1 = nsj1;
    }

#pragma unroll
    for (int f = 0; f < 2; ++f) {
        if (row16 == 0) {
#pragma unroll
            for (int q = 0; q < 4; ++q) {
                const int ir = i0 + f*16 + quad*4 + q;
                if (USE_PART) l_ws[(jsplit*NH + hh)*NN + ir] = accl[f][q];
                else          atomicAdd(&l_ws[hh*NN + ir], accl[f][q]);
            }
        }
    }
    if (USE_PART) {
        // f32 wave-native partials: 256B coalesced stores
        float* pw = outp + ((size_t)((jsplit*NH + hh)*NGRP + (i0 >> 5))) * 2048 + lane;
#pragma unroll
        for (int f = 0; f < 2; ++f)
#pragma unroll
            for (int ob = 0; ob < 4; ++ob)
#pragma unroll
                for (int q = 0; q < 4; ++q)
                    pw[((f*4 + ob)*4 + q)*64] = acc[f][ob][q];
    } else {
#pragma unroll
        for (int f = 0; f < 2; ++f)
#pragma unroll
            for (int ob = 0; ob < 4; ++ob)
#pragma unroll
                for (int q = 0; q < 4; ++q) {
                    const int grow = i0 + f*16 + quad*4 + q;
                    const int gcol = hh*OUTF + ob*16 + row16;
                    atomicAdd(&outp[(size_t)grow*256 + gcol], acc[f][ob][q]);
                }
    }
}

// ---------------------------------------------------------------------------
// K4 (partials): unscramble f32 wave-native partials, out = sum/sum(l)
// ---------------------------------------------------------------------------
__global__ __launch_bounds__(256) void k4_part(const float* __restrict__ part,
                                               const float* __restrict__ l_ws,
                                               float* __restrict__ out)
{
    const int idx = blockIdx.x * 256 + threadIdx.x;   // f32x4 index, < 262144
    const int n = idx >> 6, c4 = idx & 63;
    const int h = c4 >> 4, k = c4 & 15;
    const int g = n >> 5, f = (n >> 4) & 1, quad = (n >> 2) & 3, q = n & 3;
    const int ob = k >> 2, lb = quad*16 + (k & 3)*4;

    float L = 0.f;
    f32x4 v = {0,0,0,0};
#pragma unroll
    for (int sp = 0; sp < NSPL; ++sp) {
        L += l_ws[(sp*NH + h)*NN + n];
        const float* p = part + ((size_t)((sp*NH + h)*NGRP + g))*2048
                              + ((f*4 + ob)*4 + q)*64 + lb;
        v += *reinterpret_cast<const f32x4*>(p);
    }
    const float inv = 1.0f / L;
    *reinterpret_cast<f32x4*>(out + (size_t)n*256 + c4*4) = v * inv;
}

// K4 (atomic fallback): out /= l
__global__ __launch_bounds__(256) void k4_atomic(float* __restrict__ out,
                                                 const float* __restrict__ l_acc)
{
    const int idx = blockIdx.x * 256 + threadIdx.x;
    const int n = idx >> 6, c4 = idx & 63, h = c4 >> 4;
    const float inv = 1.0f / l_acc[h*NN + n];
    f32x4 v = *reinterpret_cast<f32x4*>(out + (size_t)n*256 + c4*4);
    *reinterpret_cast<f32x4*>(out + (size_t)n*256 + c4*4) = v * inv;
}

extern "C" void kernel_launch(void* const* d_in, const int* in_sizes, int n_in,
                              void* d_out, int out_size, void* d_ws, size_t ws_size,
                              hipStream_t stream)
{
    const float* x   = (const float*)d_in[0];
    const float* adj = (const float*)d_in[1];
    const float* W   = (const float*)d_in[2];
    const float* a   = (const float*)d_in[3];
    float* out = (float*)d_out;

    char* ws = (char*)d_ws;
    _Float16* whB  = (_Float16*)ws;                              // 2 MB
    unsigned* pack = (unsigned*)(ws + (2u<<20));                 // 2 MB
    _Float16* wBh  = (_Float16*)(ws + (4u<<20));                 // 128 KB
    _Float16* wBl  = (_Float16*)(ws + (4u<<20) + (128u<<10));    // 128 KB
    float* s_src   = (float*)(ws + (4u<<20) + (256u<<10));       // 64 KB
    float* s_dst   = (float*)(ws + (4u<<20) + (320u<<10));       // 64 KB
    unsigned* smax = (unsigned*)(ws + (4u<<20) + (384u<<10));    // 1 KB slot
    float* l_ws    = (float*)(ws + (4u<<20) + (385u<<10));       // 512 KB
    float* part    = (float*)(ws + (4u<<20) + (897u<<10));       // 32 MB (f32)

    const size_t need = (4u<<20) + (897u<<10) + (size_t)NSPL * NN * 256 * 4;

    kW_tr<<<32, 256, 0, stream>>>(W, wBh, wBl, smax);
    k01  <<<256 + NN, 256, 0, stream>>>(adj, pack, x, wBh, wBl, a,
                                        whB, s_src, s_dst, smax);

    if (ws_size >= need) {
        k3_attn<1><<<1024, 256, 0, stream>>>(pack, whB, s_src, s_dst, smax, part, l_ws);
        k4_part<<<1024, 256, 0, stream>>>(part, l_ws, out);
    } else {
        (void)hipMemsetAsync(d_out, 0, (size_t)out_size * sizeof(float), stream);
        (void)hipMemsetAsync(l_ws, 0, NH * NN * sizeof(float), stream);
        k3_attn<0><<<1024, 256, 0, stream>>>(pack, whB, s_src, s_dst, smax, out, l_ws);
        k4_atomic<<<1024, 256, 0, stream>>>(out, l_ws);
    }
}